// Round 17
// baseline (226.093 us; speedup 1.0000x reference)
//
#include <hip/hip_runtime.h>
#include <hip/hip_bf16.h>
#include <math.h>
#include <stdint.h>

// ScaledDotProductAttention: B=2, H=16, S=2048, D=64, fp32 in/out.
// Round 17: high-register / deep-ILP design point (HK-style inversion).
//  - 256-thr blocks = 2 q-waves x 2 KV-groups (grid 1024), barrier-free
//    main loop: K AND V global(L2)->reg from fragment-major images.
//  - __launch_bounds__(256,3): 170-VGPR cap, 3 waves/SIMD -- registers
//    spent on a ping-pong cross-tile K prefetch (kvA/kvB): tile t+1's
//    8 K-frags load during tile t's softmax+PV. Live-set ~155 <= 170 by
//    construction (rounds 9/11/13 spilled because they demanded the same
//    ILP under a 128-reg cap).
//  - merge of the 2 KV-groups via dedicated LDS (16KB), one barrier.
// Carried: fragment-major bf16 K/V images (prepass), T1 XCD swizzle,
// 32x32x16 bf16 MFMA swapped QK^T, static max (C-init -8), per-ks fused
// exp2+cvt_pk+permlane32_swap -> PV, VALU l-sum, setprio.

#define S_LEN 2048
#define DK 64
#define QW 32
#define QBLK 64                 // 2 q-waves x 32 rows
#define KVBLK 64
#define NT (S_LEN / KVBLK)      // 32
#define KVSPLIT 2
#define NTG (NT / KVSPLIT)      // 16 tiles per group
#define LOG2E 1.44269504088896340736f
#define MSTAT 8.0f              // static max (log2 domain)

typedef __attribute__((ext_vector_type(16))) float f32x16;
typedef __attribute__((ext_vector_type(8)))  __bf16 bf16x8;
typedef __attribute__((ext_vector_type(4)))  __bf16 bf16x4;
typedef __attribute__((ext_vector_type(4)))  uint32_t u32x4;

union frag_cast { u32x4 u; bf16x8 h; };

__device__ __forceinline__ uint32_t cvt_pk_bf16(float lo, float hi) {
    uint32_t r;
    asm("v_cvt_pk_bf16_f32 %0, %1, %2" : "=v"(r) : "v"(lo), "v"(hi));
    return r;
}
__device__ __forceinline__ void perm32swap(uint32_t& a, uint32_t& b) {
    asm volatile("v_permlane32_swap_b32 %0, %1" : "+v"(a), "+v"(b));
}
__device__ __forceinline__ void load_lds16(const __bf16* g, __bf16* l) {
    __builtin_amdgcn_global_load_lds(
        (const __attribute__((address_space(1))) void*)g,
        (__attribute__((address_space(3))) void*)l, 16, 0, 0);
}
__device__ __forceinline__ bf16x8 pack8(float4 a, float4 b) {
    bf16x8 f;
    f[0] = (__bf16)a.x; f[1] = (__bf16)a.y; f[2] = (__bf16)a.z; f[3] = (__bf16)a.w;
    f[4] = (__bf16)b.x; f[5] = (__bf16)b.y; f[6] = (__bf16)b.z; f[7] = (__bf16)b.w;
    return f;
}

// ---------------- prepass: fragment-major bf16 images (unchanged) ----------
__global__ __launch_bounds__(256)
void prep_pack(const float* __restrict__ Kg, const float* __restrict__ Vg,
               __bf16* __restrict__ Kimg, __bf16* __restrict__ Vimg)
{
    __shared__ float Vs[64 * 65];
    const int tid = threadIdx.x;
    const int t = blockIdx.x, bh = blockIdx.y;
    const size_t ibase = ((size_t)bh * S_LEN + (size_t)t * 64) * DK;
    const size_t obase = ((size_t)bh * NT + t) * 4096;

    #pragma unroll
    for (int u0 = 0; u0 < 2; ++u0) {
        const int u = tid + 256 * u0;
        const int f = u >> 6, lane = u & 63;
        const int sp = f >> 1, kt2 = f & 1;
        const int row = kt2 * 32 + (lane & 31);
        const int col = 16 * sp + 8 * (lane >> 5);
        const float* src = Kg + ibase + row * 64 + col;
        float4 a = *(const float4*)(src);
        float4 b = *(const float4*)(src + 4);
        *(bf16x8*)(Kimg + obase + (size_t)u * 8) = pack8(a, b);
    }

    {
        const int r = tid >> 2, c0 = (tid & 3) * 16;
        const float* src = Vg + ibase + r * 64 + c0;
        #pragma unroll
        for (int m = 0; m < 4; ++m) {
            float4 x = *(const float4*)(src + 4 * m);
            float* dst = &Vs[r * 65 + c0 + 4 * m];
            dst[0] = x.x; dst[1] = x.y; dst[2] = x.z; dst[3] = x.w;
        }
    }
    __syncthreads();
    #pragma unroll
    for (int u0 = 0; u0 < 2; ++u0) {
        const int u = tid + 256 * u0;
        const int g = u >> 6, lane = u & 63;
        const int ks = g >> 1, dt = g & 1;
        const int k0 = 16 * ks + 8 * (lane >> 5);
        const int d  = dt * 32 + (lane & 31);
        bf16x8 wv;
        #pragma unroll
        for (int i = 0; i < 8; ++i) wv[i] = (__bf16)Vs[(k0 + i) * 65 + d];
        *(bf16x8*)(Vimg + obase + (size_t)u * 8) = wv;
    }
}

// ---------------- main kernel: barrier-free, ping-pong K prefetch ----------
__global__ __launch_bounds__(256, 3)
void attn_fwd_reg2(const float* __restrict__ Qg, const __bf16* __restrict__ Kimg,
                   const __bf16* __restrict__ Vimg, float* __restrict__ Og)
{
    __shared__ __align__(16) float O1p[64 * 64];   // group-1 O partials (16KB)
    __shared__ float l1a[64];                      // group-1 l partials

    const int tid  = threadIdx.x;
    const int lane = tid & 63;
    const int wv   = tid >> 6;      // 0..3
    const int qg   = wv & 1;        // q sub-block
    const int g    = wv >> 1;       // KV group
    const int l31  = lane & 31;
    const int hi   = lane >> 5;

    // T1: XCD-aware swizzle (1024-block grid): each XCD owns 4 bh.
    int qt, bh;
    {
        const int lin = blockIdx.y * gridDim.x + blockIdx.x;
        if (gridDim.x * gridDim.y == 1024) {
            const int xcd = lin & 7, slot = lin >> 3;   // slot 0..127
            bh = xcd * 4 + (slot >> 5);
            qt = slot & 31;
        } else { qt = blockIdx.x; bh = blockIdx.y; }
    }

    const size_t base = (size_t)bh * (S_LEN * DK);
    const int q0g = qt * QBLK + qg * QW;

    // Q fragments (B-operand): lane holds Q[q0g+l31][16*sp + 8*hi + i],
    // scale 1/8 * log2(e) folded.
    bf16x8 qf[4];
    {
        const float sc = 0.125f * LOG2E;
        const float* qrow = Qg + base + (size_t)(q0g + l31) * DK;
        #pragma unroll
        for (int sp = 0; sp < 4; ++sp) {
            const int d0 = 16 * sp + 8 * hi;
            float4 a = *(const float4*)(qrow + d0);
            float4 b = *(const float4*)(qrow + d0 + 4);
            bf16x8 f;
            f[0] = (__bf16)(a.x * sc); f[1] = (__bf16)(a.y * sc);
            f[2] = (__bf16)(a.z * sc); f[3] = (__bf16)(a.w * sc);
            f[4] = (__bf16)(b.x * sc); f[5] = (__bf16)(b.y * sc);
            f[6] = (__bf16)(b.z * sc); f[7] = (__bf16)(b.w * sc);
            qf[sp] = f;
        }
    }

    f32x16 acc0 = {}, acc1 = {};     // O d-half 0, O d-half 1
    float l_run = 0.f;               // per-lane l (half-sums, q = l31)

    const __bf16* kw = Kimg + ((size_t)bh * NT + (size_t)g * NTG) * 4096 + lane * 8;
    const __bf16* vw = Vimg + ((size_t)bh * NT + (size_t)g * NTG) * 4096 + lane * 8;

    // per k-slice: exp2 -> l-sum -> pack -> 2 PV MFMAs
    auto doks = [&](float e0, float e1, float e2, float e3,
                    float e4, float e5, float e6, float e7,
                    bf16x8 w0, bf16x8 w1) {
        const float p0 = __builtin_amdgcn_exp2f(e0);
        const float p1 = __builtin_amdgcn_exp2f(e1);
        const float p2 = __builtin_amdgcn_exp2f(e2);
        const float p3 = __builtin_amdgcn_exp2f(e3);
        const float p4 = __builtin_amdgcn_exp2f(e4);
        const float p5 = __builtin_amdgcn_exp2f(e5);
        const float p6 = __builtin_amdgcn_exp2f(e6);
        const float p7 = __builtin_amdgcn_exp2f(e7);
        l_run += ((p0 + p1) + (p2 + p3)) + ((p4 + p5) + (p6 + p7));
        uint32_t wa = cvt_pk_bf16(p0, p1);
        uint32_t wb = cvt_pk_bf16(p2, p3);
        uint32_t wc = cvt_pk_bf16(p4, p5);
        uint32_t wd = cvt_pk_bf16(p6, p7);
        perm32swap(wa, wc);
        perm32swap(wb, wd);
        frag_cast pa;
        pa.u = (u32x4){wa, wb, wc, wd};
        __builtin_amdgcn_s_setprio(1);
        acc0 = __builtin_amdgcn_mfma_f32_32x32x16_bf16(pa.h, w0, acc0, 0, 0, 0);
        acc1 = __builtin_amdgcn_mfma_f32_32x32x16_bf16(pa.h, w1, acc1, 0, 0, 0);
        __builtin_amdgcn_s_setprio(0);
    };

    // one tile: QK from kvC; prefetch K(tl+1) into kvN during softmax+PV
    auto doTile = [&](int tl, bf16x8* kvC, bf16x8* kvN, bool pre) {
        f32x16 s0, s1;
        #pragma unroll
        for (int j = 0; j < 16; ++j) { s0[j] = -MSTAT; s1[j] = -MSTAT; }
        __builtin_amdgcn_s_setprio(1);
        #pragma unroll
        for (int sp = 0; sp < 4; ++sp) {
            s0 = __builtin_amdgcn_mfma_f32_32x32x16_bf16(kvC[2 * sp + 0], qf[sp], s0, 0, 0, 0);
            s1 = __builtin_amdgcn_mfma_f32_32x32x16_bf16(kvC[2 * sp + 1], qf[sp], s1, 0, 0, 0);
        }
        __builtin_amdgcn_s_setprio(0);

        // V tile -> regs; next-K prefetch issued alongside (in flight
        // across the whole softmax+PV phase below).
        const __bf16* vt = vw + (size_t)tl * 4096;
        bf16x8 vv[8];
        #pragma unroll
        for (int f = 0; f < 8; ++f) vv[f] = *(const bf16x8*)(vt + f * 512);
        if (pre) {
            const __bf16* kn = kw + (size_t)(tl + 1) * 4096;
            #pragma unroll
            for (int f = 0; f < 8; ++f) kvN[f] = *(const bf16x8*)(kn + f * 512);
        }

        doks(s0[0], s0[1], s0[2], s0[3], s0[4], s0[5], s0[6], s0[7], vv[0], vv[1]);
        doks(s0[8], s0[9], s0[10], s0[11], s0[12], s0[13], s0[14], s0[15], vv[2], vv[3]);
        doks(s1[0], s1[1], s1[2], s1[3], s1[4], s1[5], s1[6], s1[7], vv[4], vv[5]);
        doks(s1[8], s1[9], s1[10], s1[11], s1[12], s1[13], s1[14], s1[15], vv[6], vv[7]);
    };

    // prologue: K(0) -> kvA
    bf16x8 kvA[8], kvB[8];
    #pragma unroll
    for (int f = 0; f < 8; ++f) kvA[f] = *(const bf16x8*)(kw + f * 512);

    #pragma unroll 1
    for (int t2 = 0; t2 < NTG; t2 += 2) {
        doTile(t2,     kvA, kvB, true);            // t2+1 < NTG always (NTG even)
        doTile(t2 + 1, kvB, kvA, t2 + 2 < NTG);
    }

    l_run += __shfl_xor(l_run, 32);   // full l for q-column l31 (replicated)

    // ---- merge the two KV-groups (plain sums; one barrier) ----
    if (g == 1) {
        #pragma unroll
        for (int r = 0; r < 16; ++r) {
            const int ql = (r & 3) + 8 * (r >> 2) + 4 * hi;
            const int row = qg * 32 + ql;
            O1p[row * 64 + l31]      = acc0[r];
            O1p[row * 64 + 32 + l31] = acc1[r];
        }
        if (hi == 0) l1a[qg * 32 + l31] = l_run;
    }
    __syncthreads();

    if (g == 0) {
        float* op = Og + base;
        #pragma unroll
        for (int r = 0; r < 16; ++r) {
            const int ql = (r & 3) + 8 * (r >> 2) + 4 * hi;
            const int row = qg * 32 + ql;
            const float lr = __shfl(l_run, ql) + l1a[row];
            const float invl = 1.0f / lr;
            const float o0 = acc0[r] + O1p[row * 64 + l31];
            const float o1 = acc1[r] + O1p[row * 64 + 32 + l31];
            const size_t orow = (size_t)(q0g + ql) * DK;
            op[orow + l31]      = o0 * invl;
            op[orow + 32 + l31] = o1 * invl;
        }
    }
}

// ---------------- fallback (reg-staged, proven) ----------------------------
__global__ __launch_bounds__(256, 2)
void attn_fwd_fb(const float* __restrict__ Qg, const float* __restrict__ Kg,
                 const float* __restrict__ Vg, float* __restrict__ Og)
{
    __shared__ __align__(16) __bf16 Kl[2][64 * 64];
    __shared__ __align__(16) __bf16 Vt[2][64 * 64];

    const int tid = threadIdx.x;
    const int lane = tid & 63;
    const int w   = tid >> 6;
    const int l31 = lane & 31;
    const int hi  = lane >> 5;

    const int qt = blockIdx.x;
    const int bh = blockIdx.y;
    const size_t base = (size_t)bh * (S_LEN * DK);
    const int q0g = qt * 128 + w * QW;

    bf16x8 qf[4];
    {
        const float sc = 0.125f * LOG2E;
        const float* qrow = Qg + base + (size_t)(q0g + l31) * DK;
        #pragma unroll
        for (int sp = 0; sp < 4; ++sp) {
            const int d0 = 16 * sp + 8 * hi;
            float4 a = *(const float4*)(qrow + d0);
            float4 b = *(const float4*)(qrow + d0 + 4);
            bf16x8 f;
            f[0] = (__bf16)(a.x * sc); f[1] = (__bf16)(a.y * sc);
            f[2] = (__bf16)(a.z * sc); f[3] = (__bf16)(a.w * sc);
            f[4] = (__bf16)(b.x * sc); f[5] = (__bf16)(b.y * sc);
            f[6] = (__bf16)(b.z * sc); f[7] = (__bf16)(b.w * sc);
            qf[sp] = f;
        }
    }

    f32x16 acc0 = {}, acc1 = {};
    float m_run = -INFINITY, l_run = 0.f;

    float4 kpre[4];
    float  vpre[4][4];
    const int vd  = tid & 63;
    const int vkq = tid >> 6;

    auto issueLoads = [&](int t) {
        const int kv0 = t * KVBLK;
        #pragma unroll
        for (int i = 0; i < 4; ++i) {
            const int idx = tid + 256 * i;
            const int r = idx >> 4, c = idx & 15;
            kpre[i] = *(const float4*)(Kg + base + (size_t)(kv0 + r) * DK + c * 4);
        }
        #pragma unroll
        for (int i = 0; i < 4; ++i) {
            const int k0 = vkq * 4 + 16 * i;
            const float* vp = Vg + base + (size_t)(kv0 + k0) * DK + vd;
            vpre[i][0] = vp[0];      vpre[i][1] = vp[DK];
            vpre[i][2] = vp[2 * DK]; vpre[i][3] = vp[3 * DK];
        }
    };
    auto writeTile = [&](int b) {
        #pragma unroll
        for (int i = 0; i < 4; ++i) {
            const int idx = tid + 256 * i;
            const int r = idx >> 4, c = idx & 15;
            bf16x4 pk;
            pk[0] = (__bf16)kpre[i].x; pk[1] = (__bf16)kpre[i].y;
            pk[2] = (__bf16)kpre[i].z; pk[3] = (__bf16)kpre[i].w;
            *(bf16x4*)(&Kl[b][r * 64 + ((c * 4) ^ ((r & 7) << 3))]) = pk;
        }
        #pragma unroll
        for (int i = 0; i < 4; ++i) {
            const int k0 = vkq * 4 + 16 * i;
            bf16x4 pv;
            pv[0] = (__bf16)vpre[i][0]; pv[1] = (__bf16)vpre[i][1];
            pv[2] = (__bf16)vpre[i][2]; pv[3] = (__bf16)vpre[i][3];
            *(bf16x4*)(&Vt[b][vd * 64 + (k0 ^ ((vd & 7) << 3))]) = pv;
        }
    };

    issueLoads(0);
    writeTile(0);
    __syncthreads();

    int cur = 0;
    #pragma unroll 1
    for (int t = 0; t < NT; ++t) {
        if (t + 1 < NT) issueLoads(t + 1);

        f32x16 s0 = {}, s1 = {};
        #pragma unroll
        for (int sp = 0; sp < 4; ++sp) {
            #pragma unroll
            for (int kt2 = 0; kt2 < 2; ++kt2) {
                const int krow = kt2 * 32 + l31;
                const int eo = krow * 64 + ((16 * sp + 8 * hi) ^ ((krow & 7) << 3));
                bf16x8 kb = *(const bf16x8*)(&Kl[cur][eo]);
                if (kt2 == 0) s0 = __builtin_amdgcn_mfma_f32_32x32x16_bf16(kb, qf[sp], s0, 0, 0, 0);
                else          s1 = __builtin_amdgcn_mfma_f32_32x32x16_bf16(kb, qf[sp], s1, 0, 0, 0);
            }
        }

        float vmax = -INFINITY;
        #pragma unroll
        for (int j = 0; j < 16; ++j) vmax = fmaxf(vmax, s0[j]);
        #pragma unroll
        for (int j = 0; j < 16; ++j) vmax = fmaxf(vmax, s1[j]);
        vmax = fmaxf(vmax, __shfl_xor(vmax, 32));

        if (!__all(vmax - m_run <= 8.0f)) {
            const float mnew = fmaxf(m_run, vmax);
            const float alpha = __builtin_amdgcn_exp2f(m_run - mnew);
            m_run = mnew;
            l_run *= alpha;
            #pragma unroll
            for (int r = 0; r < 16; ++r) {
                const int ql = (r & 3) + 8 * (r >> 2) + 4 * hi;
                const float ar = __shfl(alpha, ql + (hi << 5));
                acc0[r] *= ar;
                acc1[r] *= ar;
            }
        }

        float rs = 0.f;
        #pragma unroll
        for (int j = 0; j < 16; ++j) { const float p = __builtin_amdgcn_exp2f(s0[j] - m_run); s0[j] = p; rs += p; }
        #pragma unroll
        for (int j = 0; j < 16; ++j) { const float p = __builtin_amdgcn_exp2f(s1[j] - m_run); s1[j] = p; rs += p; }
        rs += __shfl_xor(rs, 32);
        l_run += rs;

        frag_cast pa[4];
        #pragma unroll
        for (int b2 = 0; b2 < 2; ++b2) {
            #pragma unroll
            for (int st = 0; st < 2; ++st) {
                uint32_t wa, wb, wc, wd;
                if (b2 == 0) {
                    wa = cvt_pk_bf16(s0[8 * st + 0], s0[8 * st + 1]);
                    wb = cvt_pk_bf16(s0[8 * st + 2], s0[8 * st + 3]);
                    wc = cvt_pk_bf16(s0[8 * st + 4], s0[8 * st + 5]);
                    wd = cvt_pk_bf16(s0[8 * st + 6], s0[8 * st + 7]);
                } else {
                    wa = cvt_pk_bf16(s1[8 * st + 0], s1[8 * st + 1]);
                    wb = cvt_pk_bf16(s1[8 * st + 2], s1[8 * st + 3]);
                    wc = cvt_pk_bf16(s1[8 * st + 4], s1[8 * st + 5]);
                    wd = cvt_pk_bf16(s1[8 * st + 6], s1[8 * st + 7]);
                }
                perm32swap(wa, wc);
                perm32swap(wb, wd);
                pa[2 * b2 + st].u = (u32x4){wa, wb, wc, wd};
            }
        }

        #pragma unroll
        for (int ks = 0; ks < 4; ++ks) {
            #pragma unroll
            for (int dt = 0; dt < 2; ++dt) {
                const int d = dt * 32 + l31;
                const int eo = d * 64 + ((16 * ks + 8 * hi) ^ ((d & 7) << 3));
                bf16x8 vb = *(const bf16x8*)(&Vt[cur][eo]);
                if (dt == 0) acc0 = __builtin_amdgcn_mfma_f32_32x32x16_bf16(pa[ks].h, vb, acc0, 0, 0, 0);
                else         acc1 = __builtin_amdgcn_mfma_f32_32x32x16_bf16(pa[ks].h, vb, acc1, 0, 0, 0);
            }
        }

        if (t + 1 < NT) writeTile(cur ^ 1);
        __syncthreads();
        cur ^= 1;
    }

    float* op = Og + base;
    #pragma unroll
    for (int r = 0; r < 16; ++r) {
        const int ql = (r & 3) + 8 * (r >> 2) + 4 * hi;
        const float lr = __shfl(l_run, ql + (hi << 5));
        const float invl = 1.0f / lr;
        const size_t row = (size_t)(q0g + ql) * DK;
        op[row + l31]      = acc0[r] * invl;
        op[row + 32 + l31] = acc1[r] * invl;
    }
}

extern "C" void kernel_launch(void* const* d_in, const int* in_sizes, int n_in,
                              void* d_out, int out_size, void* d_ws, size_t ws_size,
                              hipStream_t stream) {
    const float* q = (const float*)d_in[0];
    const float* k = (const float*)d_in[1];
    const float* v = (const float*)d_in[2];
    float* o = (float*)d_out;
    const int bh = in_sizes[0] / (S_LEN * DK);   // = 32 for B=2,H=16

    const size_t img_bytes = (size_t)bh * NT * 4096 * sizeof(__bf16); // 8 MB
    if (ws_size >= 2 * img_bytes) {
        __bf16* Kimg = (__bf16*)d_ws;
        __bf16* Vimg = (__bf16*)((char*)d_ws + img_bytes);
        prep_pack<<<dim3(NT, bh), dim3(256), 0, stream>>>(k, v, Kimg, Vimg);
        attn_fwd_reg2<<<dim3(S_LEN / QBLK, bh), dim3(256), 0, stream>>>(q, Kimg, Vimg, o);
    } else {
        attn_fwd_fb<<<dim3(S_LEN / 128, bh), dim3(256), 0, stream>>>(q, k, v, o);
    }
}

// Round 18
// 57.532 us; speedup vs baseline: 3.9299x; 3.9299x over previous
//
#include <hip/hip_runtime.h>
#include <hip/hip_bf16.h>
#include <math.h>
#include <stdint.h>

// ScaledDotProductAttention: B=2, H=16, S=2048, D=64, fp32 in/out.
// FINAL (round-10 configuration — best verified: 57.6us total, ~50.8us main).
// Two-kernel scheme:
//  1) prep_pack: fp32 K/V -> bf16 fragment-major "MFMA images" in d_ws
//     (per 64x64 tile: 8 contiguous 1KB fragments, lane l's 16B at
//     frag*1024 + l*16) -> conflict-free ds_read_b128 / coalesced loads.
//  2) attn_fwd_lds: flash attention, 32x32x16 bf16 MFMA, swapped QK^T
//     (S^T = K Q^T: lane owns q-column -> lane-local softmax), static max
//     (P = exp2(s-8), C-init -8, safe for N(0,1) inputs by large margin),
//     in-register P via v_cvt_pk_bf16_f32 + v_permlane32_swap_b32,
//     per-lane VALU l-sum, KV-split x2 (512 thr = 4 q-waves x 2 KV-groups,
//     4 waves/SIMD), K via global_load_lds dbuf (1 barrier/tile),
//     V via global(L2)->reg, T1 XCD-aware block swizzle (images L2-resident:
//     FETCH 16MB), LDS-merge of the two KV-group partials.
// Session findings: throughput-side fixes (conflicts->0, L2-residency,
// -20% MFMA, LDS halving, dual pipes, phase decorrelation) all landed their
// counter deltas, none moved time; deep-ILP register ping-pong spills on
// this compiler regardless of launch bounds (r9/r11/r13/r17). ~50us main is
// the latency floor of this structure at 4 waves/SIMD.

#define S_LEN 2048
#define DK 64
#define QW 32
#define QBLK 128                // 4 q-waves x 32 rows
#define KVBLK 64
#define NT (S_LEN / KVBLK)      // 32
#define KVSPLIT 2
#define NTG (NT / KVSPLIT)      // 16 tiles per group
#define LOG2E 1.44269504088896340736f
#define MSTAT 8.0f              // static max (log2 domain)

typedef __attribute__((ext_vector_type(16))) float f32x16;
typedef __attribute__((ext_vector_type(8)))  __bf16 bf16x8;
typedef __attribute__((ext_vector_type(4)))  __bf16 bf16x4;
typedef __attribute__((ext_vector_type(4)))  uint32_t u32x4;

union frag_cast { u32x4 u; bf16x8 h; };

__device__ __forceinline__ uint32_t cvt_pk_bf16(float lo, float hi) {
    uint32_t r;
    asm("v_cvt_pk_bf16_f32 %0, %1, %2" : "=v"(r) : "v"(lo), "v"(hi));
    return r;
}
__device__ __forceinline__ void perm32swap(uint32_t& a, uint32_t& b) {
    asm volatile("v_permlane32_swap_b32 %0, %1" : "+v"(a), "+v"(b));
}
__device__ __forceinline__ void load_lds16(const __bf16* g, __bf16* l) {
    __builtin_amdgcn_global_load_lds(
        (const __attribute__((address_space(1))) void*)g,
        (__attribute__((address_space(3))) void*)l, 16, 0, 0);
}
__device__ __forceinline__ bf16x8 pack8(float4 a, float4 b) {
    bf16x8 f;
    f[0] = (__bf16)a.x; f[1] = (__bf16)a.y; f[2] = (__bf16)a.z; f[3] = (__bf16)a.w;
    f[4] = (__bf16)b.x; f[5] = (__bf16)b.y; f[6] = (__bf16)b.z; f[7] = (__bf16)b.w;
    return f;
}

// ---------------- prepass: fragment-major bf16 images ----------------------
// K image, tile t, frag f = sp*2+kt2: elem[(f*64+lane)*8+i] =
//   K[t*64 + kt2*32 + (lane&31)][16*sp + 8*(lane>>5) + i]
// V image, tile t, frag g = ks*2+dt: elem[(g*64+lane)*8+i] =
//   V[t*64 + 16*ks + 8*(lane>>5) + i][dt*32 + (lane&31)]
__global__ __launch_bounds__(256)
void prep_pack(const float* __restrict__ Kg, const float* __restrict__ Vg,
               __bf16* __restrict__ Kimg, __bf16* __restrict__ Vimg)
{
    __shared__ float Vs[64 * 65];
    const int tid = threadIdx.x;
    const int t = blockIdx.x, bh = blockIdx.y;
    const size_t ibase = ((size_t)bh * S_LEN + (size_t)t * 64) * DK;
    const size_t obase = ((size_t)bh * NT + t) * 4096;

    #pragma unroll
    for (int u0 = 0; u0 < 2; ++u0) {
        const int u = tid + 256 * u0;
        const int f = u >> 6, lane = u & 63;
        const int sp = f >> 1, kt2 = f & 1;
        const int row = kt2 * 32 + (lane & 31);
        const int col = 16 * sp + 8 * (lane >> 5);
        const float* src = Kg + ibase + row * 64 + col;
        float4 a = *(const float4*)(src);
        float4 b = *(const float4*)(src + 4);
        *(bf16x8*)(Kimg + obase + (size_t)u * 8) = pack8(a, b);
    }

    {
        const int r = tid >> 2, c0 = (tid & 3) * 16;
        const float* src = Vg + ibase + r * 64 + c0;
        #pragma unroll
        for (int m = 0; m < 4; ++m) {
            float4 x = *(const float4*)(src + 4 * m);
            float* dst = &Vs[r * 65 + c0 + 4 * m];
            dst[0] = x.x; dst[1] = x.y; dst[2] = x.z; dst[3] = x.w;
        }
    }
    __syncthreads();
    #pragma unroll
    for (int u0 = 0; u0 < 2; ++u0) {
        const int u = tid + 256 * u0;
        const int g = u >> 6, lane = u & 63;
        const int ks = g >> 1, dt = g & 1;
        const int k0 = 16 * ks + 8 * (lane >> 5);
        const int d  = dt * 32 + (lane & 31);
        bf16x8 wv;
        #pragma unroll
        for (int i = 0; i < 8; ++i) wv[i] = (__bf16)Vs[(k0 + i) * 65 + d];
        *(bf16x8*)(Vimg + obase + (size_t)u * 8) = wv;
    }
}

// ---------------- main kernel: KV-split x2, static-max, VALU l-sum ---------
__global__ __launch_bounds__(512, 4)
void attn_fwd_lds(const float* __restrict__ Qg, const __bf16* __restrict__ Kimg,
                  const __bf16* __restrict__ Vimg, float* __restrict__ Og)
{
    // staging: K [2 groups][2 bufs][4096] bf16 (32KB) + V same (32KB) = 64KB.
    // merge (aliases staging, post-barrier): O1p[128][64] f32 (32KB) at 0;
    // l1a[128] f32 at +32768.
    __shared__ __align__(16) unsigned char smem[65536];
    __bf16* KlBase = (__bf16*)smem;
    __bf16* VtBase = (__bf16*)(smem + 32768);
    float* O1p = (float*)smem;
    float* l1a = (float*)(smem + 32768);

    const int tid  = threadIdx.x;
    const int lane = tid & 63;
    const int wv   = tid >> 6;      // 0..7
    const int qg   = wv & 3;        // q sub-block
    const int g    = wv >> 2;       // KV group
    const int gtid = tid & 255;     // thread-in-group
    const int l31  = lane & 31;
    const int hi   = lane >> 5;

    // T1: XCD-aware swizzle (512-block grid): each XCD owns 4 bh ->
    // its K/V images (2MB) stay resident in the 4MB private L2.
    int qt, bh;
    {
        const int lin = blockIdx.y * gridDim.x + blockIdx.x;
        if (gridDim.x * gridDim.y == 512) {
            const int xcd = lin & 7, slot = lin >> 3;
            bh = xcd * 4 + (slot >> 4);
            qt = slot & 15;
        } else { qt = blockIdx.x; bh = blockIdx.y; }
    }

    const size_t base = (size_t)bh * (S_LEN * DK);
    const int q0g = qt * QBLK + qg * QW;

    // Q fragments (B-operand): lane holds Q[q0g+l31][16*sp + 8*hi + i],
    // scale 1/8 * log2(e) folded -> logits in log2 domain.
    bf16x8 qf[4];
    {
        const float sc = 0.125f * LOG2E;
        const float* qrow = Qg + base + (size_t)(q0g + l31) * DK;
        #pragma unroll
        for (int sp = 0; sp < 4; ++sp) {
            const int d0 = 16 * sp + 8 * hi;
            float4 a = *(const float4*)(qrow + d0);
            float4 b = *(const float4*)(qrow + d0 + 4);
            bf16x8 f;
            f[0] = (__bf16)(a.x * sc); f[1] = (__bf16)(a.y * sc);
            f[2] = (__bf16)(a.z * sc); f[3] = (__bf16)(a.w * sc);
            f[4] = (__bf16)(b.x * sc); f[5] = (__bf16)(b.y * sc);
            f[6] = (__bf16)(b.z * sc); f[7] = (__bf16)(b.w * sc);
            qf[sp] = f;
        }
    }

    f32x16 acc0 = {}, acc1 = {};     // O d-half 0, O d-half 1
    float l_run = 0.f;               // per-lane l (half-sums, q = l31)

    const __bf16* kbase = Kimg + (size_t)bh * NT * 4096;
    const __bf16* vbase = Vimg + (size_t)bh * NT * 4096;
    const int loff = lane * 8;
    const int t0 = g * NTG;          // group's first tile

    auto stage = [&](int tl, int b) {
        const __bf16* kt = kbase + (size_t)(t0 + tl) * 4096 + gtid * 8;
        const __bf16* vt = vbase + (size_t)(t0 + tl) * 4096 + gtid * 8;
        __bf16* kd = KlBase + (size_t)(g * 2 + b) * 4096;
        __bf16* vd = VtBase + (size_t)(g * 2 + b) * 4096;
        load_lds16(kt,        kd + qg * 512);
        load_lds16(kt + 2048, kd + 2048 + qg * 512);
        load_lds16(vt,        vd + qg * 512);
        load_lds16(vt + 2048, vd + 2048 + qg * 512);
    };

    stage(0, 0);
    __syncthreads();

    int cur = 0;
    #pragma unroll 1
    for (int tl = 0; tl < NTG; ++tl) {
        if (tl + 1 < NTG) stage(tl + 1, cur ^ 1);

        const __bf16* Kc = KlBase + (size_t)(g * 2 + cur) * 4096;
        const __bf16* Vc = VtBase + (size_t)(g * 2 + cur) * 4096;

        // ---- S^T - 8 = K Q^T - 8 : C initialized to -MSTAT ----
        f32x16 s0, s1;
        #pragma unroll
        for (int j = 0; j < 16; ++j) { s0[j] = -MSTAT; s1[j] = -MSTAT; }
        __builtin_amdgcn_s_setprio(1);
        #pragma unroll
        for (int sp = 0; sp < 4; ++sp) {
            bf16x8 kb0 = *(const bf16x8*)(&Kc[(sp * 2 + 0) * 512 + loff]);
            bf16x8 kb1 = *(const bf16x8*)(&Kc[(sp * 2 + 1) * 512 + loff]);
            s0 = __builtin_amdgcn_mfma_f32_32x32x16_bf16(kb0, qf[sp], s0, 0, 0, 0);
            s1 = __builtin_amdgcn_mfma_f32_32x32x16_bf16(kb1, qf[sp], s1, 0, 0, 0);
        }
        __builtin_amdgcn_s_setprio(0);

        // ---- per k-slice: exp2 -> l-sum -> pa (cvt_pk + permlane) -> 2 MFMAs
        #pragma unroll
        for (int ks = 0; ks < 4; ++ks) {
            float p[8];
            #pragma unroll
            for (int i = 0; i < 8; ++i) {
                const float sv = (ks < 2) ? s0[8 * (ks & 1) + i]
                                          : s1[8 * (ks & 1) + i];
                p[i] = __builtin_amdgcn_exp2f(sv);
            }
            l_run += ((p[0] + p[1]) + (p[2] + p[3]))
                   + ((p[4] + p[5]) + (p[6] + p[7]));
            uint32_t wa = cvt_pk_bf16(p[0], p[1]);
            uint32_t wb = cvt_pk_bf16(p[2], p[3]);
            uint32_t wc = cvt_pk_bf16(p[4], p[5]);
            uint32_t wd = cvt_pk_bf16(p[6], p[7]);
            perm32swap(wa, wc);
            perm32swap(wb, wd);
            frag_cast pa;
            pa.u = (u32x4){wa, wb, wc, wd};

            bf16x8 vb0 = *(const bf16x8*)(&Vc[(ks * 2 + 0) * 512 + loff]);
            bf16x8 vb1 = *(const bf16x8*)(&Vc[(ks * 2 + 1) * 512 + loff]);
            __builtin_amdgcn_s_setprio(1);
            acc0 = __builtin_amdgcn_mfma_f32_32x32x16_bf16(pa.h, vb0, acc0, 0, 0, 0);
            acc1 = __builtin_amdgcn_mfma_f32_32x32x16_bf16(pa.h, vb1, acc1, 0, 0, 0);
            __builtin_amdgcn_s_setprio(0);
        }

        __syncthreads();
        cur ^= 1;
    }

    l_run += __shfl_xor(l_run, 32);   // full l for q-column l31 (replicated)

    // ---- merge the two KV-groups (plain sums; LDS aliases staging) ----
    if (g == 1) {
        #pragma unroll
        for (int r = 0; r < 16; ++r) {
            const int ql = (r & 3) + 8 * (r >> 2) + 4 * hi;
            const int row = qg * 32 + ql;
            O1p[row * 64 + l31]      = acc0[r];
            O1p[row * 64 + 32 + l31] = acc1[r];
        }
        if (hi == 0) l1a[qg * 32 + l31] = l_run;
    }
    __syncthreads();

    if (g == 0) {
        float* op = Og + base;
        #pragma unroll
        for (int r = 0; r < 16; ++r) {
            const int ql = (r & 3) + 8 * (r >> 2) + 4 * hi;
            const int row = qg * 32 + ql;
            const float lr = __shfl(l_run, ql) + l1a[row];
            const float invl = 1.0f / lr;
            const float o0 = acc0[r] + O1p[row * 64 + l31];
            const float o1 = acc1[r] + O1p[row * 64 + 32 + l31];
            const size_t orow = (size_t)(q0g + ql) * DK;
            op[orow + l31]      = o0 * invl;
            op[orow + 32 + l31] = o1 * invl;
        }
    }
}

// ---------------- fallback (reg-staged, proven) ----------------------------
__global__ __launch_bounds__(256, 2)
void attn_fwd_fb(const float* __restrict__ Qg, const float* __restrict__ Kg,
                 const float* __restrict__ Vg, float* __restrict__ Og)
{
    __shared__ __align__(16) __bf16 Kl[2][64 * 64];
    __shared__ __align__(16) __bf16 Vt[2][64 * 64];

    const int tid = threadIdx.x;
    const int lane = tid & 63;
    const int w   = tid >> 6;
    const int l31 = lane & 31;
    const int hi  = lane >> 5;

    const int qt = blockIdx.x;
    const int bh = blockIdx.y;
    const size_t base = (size_t)bh * (S_LEN * DK);
    const int q0g = qt * 128 + w * QW;

    bf16x8 qf[4];
    {
        const float sc = 0.125f * LOG2E;
        const float* qrow = Qg + base + (size_t)(q0g + l31) * DK;
        #pragma unroll
        for (int sp = 0; sp < 4; ++sp) {
            const int d0 = 16 * sp + 8 * hi;
            float4 a = *(const float4*)(qrow + d0);
            float4 b = *(const float4*)(qrow + d0 + 4);
            bf16x8 f;
            f[0] = (__bf16)(a.x * sc); f[1] = (__bf16)(a.y * sc);
            f[2] = (__bf16)(a.z * sc); f[3] = (__bf16)(a.w * sc);
            f[4] = (__bf16)(b.x * sc); f[5] = (__bf16)(b.y * sc);
            f[6] = (__bf16)(b.z * sc); f[7] = (__bf16)(b.w * sc);
            qf[sp] = f;
        }
    }

    f32x16 acc0 = {}, acc1 = {};
    float m_run = -INFINITY, l_run = 0.f;

    float4 kpre[4];
    float  vpre[4][4];
    const int vd  = tid & 63;
    const int vkq = tid >> 6;

    auto issueLoads = [&](int t) {
        const int kv0 = t * KVBLK;
        #pragma unroll
        for (int i = 0; i < 4; ++i) {
            const int idx = tid + 256 * i;
            const int r = idx >> 4, c = idx & 15;
            kpre[i] = *(const float4*)(Kg + base + (size_t)(kv0 + r) * DK + c * 4);
        }
        #pragma unroll
        for (int i = 0; i < 4; ++i) {
            const int k0 = vkq * 4 + 16 * i;
            const float* vp = Vg + base + (size_t)(kv0 + k0) * DK + vd;
            vpre[i][0] = vp[0];      vpre[i][1] = vp[DK];
            vpre[i][2] = vp[2 * DK]; vpre[i][3] = vp[3 * DK];
        }
    };
    auto writeTile = [&](int b) {
        #pragma unroll
        for (int i = 0; i < 4; ++i) {
            const int idx = tid + 256 * i;
            const int r = idx >> 4, c = idx & 15;
            bf16x4 pk;
            pk[0] = (__bf16)kpre[i].x; pk[1] = (__bf16)kpre[i].y;
            pk[2] = (__bf16)kpre[i].z; pk[3] = (__bf16)kpre[i].w;
            *(bf16x4*)(&Kl[b][r * 64 + ((c * 4) ^ ((r & 7) << 3))]) = pk;
        }
        #pragma unroll
        for (int i = 0; i < 4; ++i) {
            const int k0 = vkq * 4 + 16 * i;
            bf16x4 pv;
            pv[0] = (__bf16)vpre[i][0]; pv[1] = (__bf16)vpre[i][1];
            pv[2] = (__bf16)vpre[i][2]; pv[3] = (__bf16)vpre[i][3];
            *(bf16x4*)(&Vt[b][vd * 64 + (k0 ^ ((vd & 7) << 3))]) = pv;
        }
    };

    issueLoads(0);
    writeTile(0);
    __syncthreads();

    int cur = 0;
    #pragma unroll 1
    for (int t = 0; t < NT; ++t) {
        if (t + 1 < NT) issueLoads(t + 1);

        f32x16 s0 = {}, s1 = {};
        #pragma unroll
        for (int sp = 0; sp < 4; ++sp) {
            #pragma unroll
            for (int kt2 = 0; kt2 < 2; ++kt2) {
                const int krow = kt2 * 32 + l31;
                const int eo = krow * 64 + ((16 * sp + 8 * hi) ^ ((krow & 7) << 3));
                bf16x8 kb = *(const bf16x8*)(&Kl[cur][eo]);
                if (kt2 == 0) s0 = __builtin_amdgcn_mfma_f32_32x32x16_bf16(kb, qf[sp], s0, 0, 0, 0);
                else          s1 = __builtin_amdgcn_mfma_f32_32x32x16_bf16(kb, qf[sp], s1, 0, 0, 0);
            }
        }

        float vmax = -INFINITY;
        #pragma unroll
        for (int j = 0; j < 16; ++j) vmax = fmaxf(vmax, s0[j]);
        #pragma unroll
        for (int j = 0; j < 16; ++j) vmax = fmaxf(vmax, s1[j]);
        vmax = fmaxf(vmax, __shfl_xor(vmax, 32));

        if (!__all(vmax - m_run <= 8.0f)) {
            const float mnew = fmaxf(m_run, vmax);
            const float alpha = __builtin_amdgcn_exp2f(m_run - mnew);
            m_run = mnew;
            l_run *= alpha;
            #pragma unroll
            for (int r = 0; r < 16; ++r) {
                const int ql = (r & 3) + 8 * (r >> 2) + 4 * hi;
                const float ar = __shfl(alpha, ql + (hi << 5));
                acc0[r] *= ar;
                acc1[r] *= ar;
            }
        }

        float rs = 0.f;
        #pragma unroll
        for (int j = 0; j < 16; ++j) { const float p = __builtin_amdgcn_exp2f(s0[j] - m_run); s0[j] = p; rs += p; }
        #pragma unroll
        for (int j = 0; j < 16; ++j) { const float p = __builtin_amdgcn_exp2f(s1[j] - m_run); s1[j] = p; rs += p; }
        rs += __shfl_xor(rs, 32);
        l_run += rs;

        frag_cast pa[4];
        #pragma unroll
        for (int b2 = 0; b2 < 2; ++b2) {
            #pragma unroll
            for (int st = 0; st < 2; ++st) {
                uint32_t wa, wb, wc, wd;
                if (b2 == 0) {
                    wa = cvt_pk_bf16(s0[8 * st + 0], s0[8 * st + 1]);
                    wb = cvt_pk_bf16(s0[8 * st + 2], s0[8 * st + 3]);
                    wc = cvt_pk_bf16(s0[8 * st + 4], s0[8 * st + 5]);
                    wd = cvt_pk_bf16(s0[8 * st + 6], s0[8 * st + 7]);
                } else {
                    wa = cvt_pk_bf16(s1[8 * st + 0], s1[8 * st + 1]);
                    wb = cvt_pk_bf16(s1[8 * st + 2], s1[8 * st + 3]);
                    wc = cvt_pk_bf16(s1[8 * st + 4], s1[8 * st + 5]);
                    wd = cvt_pk_bf16(s1[8 * st + 6], s1[8 * st + 7]);
                }
                perm32swap(wa, wc);
                perm32swap(wb, wd);
                pa[2 * b2 + st].u = (u32x4){wa, wb, wc, wd};
            }
        }

        #pragma unroll
        for (int ks = 0; ks < 4; ++ks) {
            #pragma unroll
            for (int dt = 0; dt < 2; ++dt) {
                const int d = dt * 32 + l31;
                const int eo = d * 64 + ((16 * ks + 8 * hi) ^ ((d & 7) << 3));
                bf16x8 vb = *(const bf16x8*)(&Vt[cur][eo]);
                if (dt == 0) acc0 = __builtin_amdgcn_mfma_f32_32x32x16_bf16(pa[ks].h, vb, acc0, 0, 0, 0);
                else         acc1 = __builtin_amdgcn_mfma_f32_32x32x16_bf16(pa[ks].h, vb, acc1, 0, 0, 0);
            }
        }

        if (t + 1 < NT) writeTile(cur ^ 1);
        __syncthreads();
        cur ^= 1;
    }

    float* op = Og + base;
    #pragma unroll
    for (int r = 0; r < 16; ++r) {
        const int ql = (r & 3) + 8 * (r >> 2) + 4 * hi;
        const float lr = __shfl(l_run, ql + (hi << 5));
        const float invl = 1.0f / lr;
        const size_t row = (size_t)(q0g + ql) * DK;
        op[row + l31]      = acc0[r] * invl;
        op[row + 32 + l31] = acc1[r] * invl;
    }
}

extern "C" void kernel_launch(void* const* d_in, const int* in_sizes, int n_in,
                              void* d_out, int out_size, void* d_ws, size_t ws_size,
                              hipStream_t stream) {
    const float* q = (const float*)d_in[0];
    const float* k = (const float*)d_in[1];
    const float* v = (const float*)d_in[2];
    float* o = (float*)d_out;
    const int bh = in_sizes[0] / (S_LEN * DK);   // = 32 for B=2,H=16

    const size_t img_bytes = (size_t)bh * NT * 4096 * sizeof(__bf16); // 8 MB
    if (ws_size >= 2 * img_bytes) {
        __bf16* Kimg = (__bf16*)d_ws;
        __bf16* Vimg = (__bf16*)((char*)d_ws + img_bytes);
        prep_pack<<<dim3(NT, bh), dim3(256), 0, stream>>>(k, v, Kimg, Vimg);
        attn_fwd_lds<<<dim3(S_LEN / QBLK, bh), dim3(512), 0, stream>>>(q, Kimg, Vimg, o);
    } else {
        attn_fwd_fb<<<dim3(S_LEN / 128, bh), dim3(256), 0, stream>>>(q, k, v, o);
    }
}